// Round 4
// baseline (178.281 us; speedup 1.0000x reference)
//
#include <hip/hip_runtime.h>
#include <hip/hip_bf16.h>

// Problem constants: features [16, 512, 56, 56] f32, k=3 -> d=1
#define BB 16
#define CC 512
#define HH 56
#define WW 56
#define HW (HH * WW)
#define NPIX (BB * HW)
#define PXB 448        // pixels per block: 8 rows x 56
#define NLDS (6 * PXB) // 2688 floats

// Thread owns a 2-row x 4-col patch; streams 6 rows (ys-2..ys+3, clamped) per
// channel. ALL taps in-register (separable conv order swap):
//   h1(y,x)=mxm g(y,cl(x-2))+g(y,cl(x-1))+mxp g(y,x)
//   h2(y,x)=mxm g(y,x)+g(y,cl(x+1))+mxp g(y,cl(x+2))
//   hv(y,x)=mxm g(y,cl(x-1))+g(y,x)+mxp g(y,cl(x+1))
//   f1(y)=mym h1(y-1)+h1(y)+myp h1(y+1); f2 same with h2
//   f3(y)=mym hv(y)+hv(cl(y+1))+myp hv(cl(y+2))
//   f4(y)=mym hv(cl(y-2))+hv(cl(y-1))+myp hv(y)
// (masked terms use clamped-row values with coefficient 0 -> safe.)
// Lane = s*16 + q16: s = 2-row strip 0..3 (rows ybase+2s..+2s+1), q16 = x-quad
// (0..13 active). Block = 4 waves, same 448 px, different 16-channel groups;
// LDS reduce; then coalesced global atomics (8 cgroups -> 2.4M total).
template <int CPW, bool WRITE_OUT>
__global__ __launch_bounds__(256, 4) void ComputeTotalSim_84267258347855_kernel(
    const float* __restrict__ feat, float* __restrict__ acc, float* __restrict__ out) {
    const int tid = threadIdx.x;
    const int wave = tid >> 6;
    const int lane = tid & 63;
    const int s = lane >> 4;
    const int q16 = lane & 15;
    const bool active = q16 < 14;
    const int q = active ? q16 : 13;  // idle lanes clone q=13 (safe addresses)
    const int b = blockIdx.z;
    const int ybase = blockIdx.y * 8;
    const int ys = ybase + 2 * s;
    const int x0 = 4 * q;

    // Only possible 0-masks: mym(ys) [o=0], myp(ys+1) [o=1], mxm(j=0), mxp(j=3)
    const float mym0 = (ys >= 1) ? 1.f : 0.f;
    const float myp1 = (ys <= 53) ? 1.f : 0.f;
    const float mxm0 = (q == 0) ? 0.f : 1.f;
    const float mxp3 = (q == 13) ? 0.f : 1.f;

    int ro[6];
#pragma unroll
    for (int i = 0; i < 6; ++i) {
        int r = ys - 2 + i;
        r = r < 0 ? 0 : (r > HH - 1 ? HH - 1 : r);
        ro[i] = r * WW;
    }
    const int offA = (q == 0) ? 0 : x0 - 2;        // 8B aligned
    const int offB = (q == 13) ? x0 + 2 : x0 + 4;  // 8B aligned

    const float* p = feat +
        ((size_t)b * CC + (size_t)blockIdx.x * (4 * CPW) + (size_t)wave * CPW) * HW;

    __shared__ float lds[NLDS];
    for (int k = tid; k < NLDS; k += 256) lds[k] = 0.f;
    __syncthreads();

    float s12h[2][4], s11[2][4], s22[2][4], s12v[2][4], s33[2][4], s44[2][4];
#pragma unroll
    for (int o = 0; o < 2; ++o)
#pragma unroll
        for (int j = 0; j < 4; ++j) {
            s12h[o][j] = 0.f; s11[o][j] = 0.f; s22[o][j] = 0.f;
            s12v[o][j] = 0.f; s33[o][j] = 0.f; s44[o][j] = 0.f;
        }

    for (int c = 0; c < CPW; ++c, p += HW) {
        float f1[2][4], f2[2][4], f3[2][4], f4[2][4];
#pragma unroll
        for (int i = 0; i < 6; ++i) {
            const float* pr = p + ro[i];
            const float2 A  = *(const float2*)(pr + offA);
            const float4 M  = *(const float4*)(pr + x0);
            const float2 Bv = *(const float2*)(pr + offB);
            const float L0 = A.x;
            const float L1 = (q == 0) ? A.x : A.y;
            const float L2 = M.x, L3 = M.y, L4 = M.z, L5 = M.w;
            const float L6 = (q == 13) ? Bv.y : Bv.x;
            const float L7 = Bv.y;

            float h1j[4], h2j[4], hvj[4];
            h1j[0] = fmaf(mxm0, L0, L1 + L2);
            h1j[1] = L1 + L2 + L3;
            h1j[2] = L2 + L3 + L4;
            h1j[3] = fmaf(mxp3, L5, L3 + L4);
            h2j[0] = fmaf(mxm0, L2, L3 + L4);
            h2j[1] = L3 + L4 + L5;
            h2j[2] = L4 + L5 + L6;
            h2j[3] = fmaf(mxp3, L7, L5 + L6);
            hvj[0] = fmaf(mxm0, L1, L2 + L3);
            hvj[1] = L2 + L3 + L4;
            hvj[2] = L3 + L4 + L5;
            hvj[3] = fmaf(mxp3, L6, L4 + L5);

#pragma unroll
            for (int o = 0; o < 2; ++o) {
                // f1,f2 <- h rows i = o+1..o+3, coefs {mym(y_o), 1, myp(y_o)}
                if (i >= o + 1 && i <= o + 3) {
                    const float c1 = (i == o + 1) ? (o ? 1.f : mym0)
                                   : ((i == o + 3) ? (o ? myp1 : 1.f) : 1.f);
#pragma unroll
                    for (int j = 0; j < 4; ++j) {
                        if (i == o + 1) { f1[o][j] = c1 * h1j[j]; f2[o][j] = c1 * h2j[j]; }
                        else { f1[o][j] = fmaf(c1, h1j[j], f1[o][j]);
                               f2[o][j] = fmaf(c1, h2j[j], f2[o][j]); }
                    }
                }
                // f3 <- hv rows i = o+2..o+4, coefs {mym, 1, myp}
                if (i >= o + 2 && i <= o + 4) {
                    const float c3 = (i == o + 2) ? (o ? 1.f : mym0)
                                   : ((i == o + 4) ? (o ? myp1 : 1.f) : 1.f);
#pragma unroll
                    for (int j = 0; j < 4; ++j) {
                        if (i == o + 2) f3[o][j] = c3 * hvj[j];
                        else f3[o][j] = fmaf(c3, hvj[j], f3[o][j]);
                    }
                }
                // f4 <- hv rows i = o..o+2, coefs {mym, 1, myp}
                if (i >= o && i <= o + 2) {
                    const float c4 = (i == o) ? (o ? 1.f : mym0)
                                   : ((i == o + 2) ? (o ? myp1 : 1.f) : 1.f);
#pragma unroll
                    for (int j = 0; j < 4; ++j) {
                        if (i == o) f4[o][j] = c4 * hvj[j];
                        else f4[o][j] = fmaf(c4, hvj[j], f4[o][j]);
                    }
                }
            }
        }
#pragma unroll
        for (int o = 0; o < 2; ++o)
#pragma unroll
            for (int j = 0; j < 4; ++j) {
                s12h[o][j] = fmaf(f1[o][j], f2[o][j], s12h[o][j]);
                s11[o][j]  = fmaf(f1[o][j], f1[o][j], s11[o][j]);
                s22[o][j]  = fmaf(f2[o][j], f2[o][j], s22[o][j]);
                s12v[o][j] = fmaf(f3[o][j], f4[o][j], s12v[o][j]);
                s33[o][j]  = fmaf(f3[o][j], f3[o][j], s33[o][j]);
                s44[o][j]  = fmaf(f4[o][j], f4[o][j], s44[o][j]);
            }
    }

    if (active) {
#pragma unroll
        for (int o = 0; o < 2; ++o)
#pragma unroll
            for (int j = 0; j < 4; ++j) {
                const int pxi = (2 * s + o) * WW + x0 + j;
                atomicAdd(&lds[0 * PXB + pxi], s12h[o][j]);
                atomicAdd(&lds[1 * PXB + pxi], s11[o][j]);
                atomicAdd(&lds[2 * PXB + pxi], s22[o][j]);
                atomicAdd(&lds[3 * PXB + pxi], s12v[o][j]);
                atomicAdd(&lds[4 * PXB + pxi], s33[o][j]);
                atomicAdd(&lds[5 * PXB + pxi], s44[o][j]);
            }
    }
    __syncthreads();

    const int base = b * HW + ybase * WW;
    if (WRITE_OUT) {
        for (int k = tid; k < PXB; k += 256) {
            const double a0 = lds[k],            a1 = lds[PXB + k],     a2 = lds[2 * PXB + k];
            const double a3 = lds[3 * PXB + k],  a4 = lds[4 * PXB + k], a5 = lds[5 * PXB + k];
            out[base + k] = (float)(0.5 * (a0 / sqrt(a1 * a2) + a3 / sqrt(a4 * a5)));
        }
    } else {
        for (int k = tid; k < NLDS; k += 256) {
            const int pl = k / PXB;
            const int pxi = k - pl * PXB;
            atomicAdd(&acc[(size_t)pl * NPIX + base + pxi], lds[k]);
        }
    }
}

__global__ void ComputeTotalSim_finalize(const float* __restrict__ acc,
                                         float* __restrict__ out) {
    const int i = blockIdx.x * blockDim.x + threadIdx.x;
    if (i < NPIX) {
        const double s12h = acc[i],            s11 = acc[NPIX + i],     s22 = acc[2 * NPIX + i];
        const double s12v = acc[3 * NPIX + i], s33 = acc[4 * NPIX + i], s44 = acc[5 * NPIX + i];
        out[i] = (float)(0.5 * (s12h / sqrt(s11 * s22) + s12v / sqrt(s33 * s44)));
    }
}

extern "C" void kernel_launch(void* const* d_in, const int* in_sizes, int n_in,
                              void* d_out, int out_size, void* d_ws, size_t ws_size,
                              hipStream_t stream) {
    const float* feat = (const float*)d_in[0];
    float* out = (float*)d_out;

    const size_t need = 6ull * NPIX * sizeof(float);
    if (ws_size >= need) {
        hipMemsetAsync(d_ws, 0, need, stream);
        dim3 grid(8, HH / 8, BB);  // 8 cgroups (64ch) x 7 strips (8 rows) x 16
        ComputeTotalSim_84267258347855_kernel<16, false>
            <<<grid, 256, 0, stream>>>(feat, (float*)d_ws, out);
        ComputeTotalSim_finalize<<<(NPIX + 255) / 256, 256, 0, stream>>>(
            (const float*)d_ws, out);
    } else {
        // Fallback: one block covers all 512 channels (4 waves x 128), direct out.
        dim3 grid(1, HH / 8, BB);
        ComputeTotalSim_84267258347855_kernel<128, true>
            <<<grid, 256, 0, stream>>>(feat, nullptr, out);
    }
}

// Round 5
// 54.509 us; speedup vs baseline: 3.2707x; 3.2707x over previous
//
#include <hip/hip_runtime.h>
#include <hip/hip_bf16.h>

// Problem constants (from setup_inputs): features [16, 512, 56, 56] f32, k=3 -> d=1
#define BB 16
#define CC 512
#define HH 56
#define WW 56
#define HW (HH * WW)
#define NPIX (BB * HW)

__device__ __forceinline__ float shfl64(float v, int srcLane) {
    return __shfl(v, srcLane, 64);
}

// Round-1 proven math (absmax 2e-3 < 9e-3), masks & 1/9 cancel in the cosine:
//   V  = mym*g(y-1) + g(y) + myp*g(y+1)
//   w3 = mym*g(y)   + g(cl(y+1)) + myp*g(cl(y+2))
//   w4 = mym*g(cl(y-2)) + g(cl(y-1)) + myp*g(y)
//   f1 = mxm*V(cl(x-2)) + V(cl(x-1)) + mxp*V(x)
//   f2 = mxm*V(x) + V(cl(x+1)) + mxp*V(cl(x+2))
//   f3 = mxm*w3(cl(x-1)) + w3(x) + mxp*w3(cl(x+1))
//   f4 = mxm*w4(cl(x-1)) + w4(x) + mxp*w4(cl(x+1))
// One wave = one row y (lane = x), CCHUNK channels, 5 coalesced scalar loads +
// 8 ds_bpermute + ~20 fma per iter. NEW vs round 1: explicit 2-stage software
// pipeline (named regs, static indices) so channel c+1's loads are in flight
// while channel c computes — round 1's 40-VGPR build serialized the loads.
template <int CCHUNK, bool WRITE_OUT>
__global__ __launch_bounds__(256) void ComputeTotalSim_84267258347855_kernel(
    const float* __restrict__ feat, float* __restrict__ acc, float* __restrict__ out) {
    const int b = blockIdx.z;
    const int wave = threadIdx.x >> 6;
    const int lane = threadIdx.x & 63;
    const int x = lane;
    const int y = blockIdx.y * 4 + wave;

    const int xc = x < WW ? x : (WW - 1);  // clamp for load safety (lanes 56..63)
    const float mxm = (x >= 1) ? 1.f : 0.f;
    const float mxp = (x <= WW - 2) ? 1.f : 0.f;
    const float mym = (y >= 1) ? 1.f : 0.f;
    const float myp = (y <= HH - 2) ? 1.f : 0.f;

    const int lm2 = x >= 2 ? x - 2 : 0;
    const int lm1 = x >= 1 ? x - 1 : 0;
    const int lp1 = (x + 1 <= WW - 1) ? x + 1 : WW - 1;
    const int lp2 = (x + 2 <= WW - 1) ? x + 2 : WW - 1;

    const int ry0 = (y - 2 < 0) ? 0 : y - 2;
    const int ry1 = (y - 1 < 0) ? 0 : y - 1;
    const int ry2 = y;
    const int ry3 = (y + 1 > HH - 1) ? HH - 1 : y + 1;
    const int ry4 = (y + 2 > HH - 1) ? HH - 1 : y + 2;

    const int o0 = ry0 * WW + xc, o1 = ry1 * WW + xc, o2 = ry2 * WW + xc,
              o3 = ry3 * WW + xc, o4 = ry4 * WW + xc;

    const float* const pbase = feat + ((size_t)b * CC + (size_t)blockIdx.x * CCHUNK) * HW;

    float s12h = 0.f, s11 = 0.f, s22 = 0.f, s12v = 0.f, s33 = 0.f, s44 = 0.f;

#define COMPUTE(r0, r1, r2, r3, r4)                                              \
    {                                                                            \
        const float V  = fmaf(mym, r1, fmaf(myp, r3, r2));                       \
        const float w3 = fmaf(mym, r2, fmaf(myp, r4, r3));                       \
        const float w4 = fmaf(mym, r0, fmaf(myp, r2, r1));                       \
        const float Vm2 = shfl64(V, lm2), Vm1 = shfl64(V, lm1);                  \
        const float Vp1 = shfl64(V, lp1), Vp2 = shfl64(V, lp2);                  \
        const float f1 = fmaf(mxm, Vm2, fmaf(mxp, V, Vm1));                      \
        const float f2 = fmaf(mxm, V, fmaf(mxp, Vp2, Vp1));                      \
        const float f3 = fmaf(mxm, shfl64(w3, lm1), fmaf(mxp, shfl64(w3, lp1), w3)); \
        const float f4 = fmaf(mxm, shfl64(w4, lm1), fmaf(mxp, shfl64(w4, lp1), w4)); \
        s12h = fmaf(f1, f2, s12h);                                               \
        s11  = fmaf(f1, f1, s11);                                                \
        s22  = fmaf(f2, f2, s22);                                                \
        s12v = fmaf(f3, f4, s12v);                                               \
        s33  = fmaf(f3, f3, s33);                                                \
        s44  = fmaf(f4, f4, s44);                                                \
    }

    // ---- 2-stage software pipeline over channels (CCHUNK is even) ----
    float a0 = pbase[o0], a1 = pbase[o1], a2 = pbase[o2], a3 = pbase[o3], a4 = pbase[o4];
    const float* p = pbase + HW;  // next channel to load (c+1)
#pragma unroll 2
    for (int c = 0; c + 2 <= CCHUNK; c += 2) {
        // prefetch channel c+1 while computing channel c
        const float b0 = p[o0], b1 = p[o1], b2 = p[o2], b3 = p[o3], b4 = p[o4];
        COMPUTE(a0, a1, a2, a3, a4);
        // prefetch channel c+2 (clamped dummy re-read on the last pair)
        const float* pn = (c + 2 < CCHUNK) ? p + HW : p;
        a0 = pn[o0]; a1 = pn[o1]; a2 = pn[o2]; a3 = pn[o3]; a4 = pn[o4];
        COMPUTE(b0, b1, b2, b3, b4);
        p = pn + HW;
    }
#undef COMPUTE

    if (x < WW && y < HH) {
        const size_t pix = (size_t)b * HW + (size_t)y * WW + x;
        if (WRITE_OUT) {
            const double num = 0.5 * ((double)s12h / sqrt((double)s11 * (double)s22) +
                                      (double)s12v / sqrt((double)s33 * (double)s44));
            out[pix] = (float)num;
        } else {
            atomicAdd(&acc[0 * NPIX + pix], s12h);
            atomicAdd(&acc[1 * NPIX + pix], s11);
            atomicAdd(&acc[2 * NPIX + pix], s22);
            atomicAdd(&acc[3 * NPIX + pix], s12v);
            atomicAdd(&acc[4 * NPIX + pix], s33);
            atomicAdd(&acc[5 * NPIX + pix], s44);
        }
    }
}

__global__ void ComputeTotalSim_finalize(const float* __restrict__ acc,
                                         float* __restrict__ out) {
    const int i = blockIdx.x * blockDim.x + threadIdx.x;
    if (i < NPIX) {
        const double s12h = acc[i],            s11 = acc[NPIX + i],     s22 = acc[2 * NPIX + i];
        const double s12v = acc[3 * NPIX + i], s33 = acc[4 * NPIX + i], s44 = acc[5 * NPIX + i];
        out[i] = (float)(0.5 * (s12h / sqrt(s11 * s22) + s12v / sqrt(s33 * s44)));
    }
}

extern "C" void kernel_launch(void* const* d_in, const int* in_sizes, int n_in,
                              void* d_out, int out_size, void* d_ws, size_t ws_size,
                              hipStream_t stream) {
    const float* feat = (const float*)d_in[0];
    float* out = (float*)d_out;

    const size_t need = 6ull * NPIX * sizeof(float);
    if (ws_size >= need) {
        // Two-phase: channel-chunked partial sums via atomics, then finalize.
        hipMemsetAsync(d_ws, 0, need, stream);
        dim3 grid(CC / 64, HH / 4, BB);  // 8 c-chunks x 14 y-strips x 16 batches = 1792
        ComputeTotalSim_84267258347855_kernel<64, false>
            <<<grid, 256, 0, stream>>>(feat, (float*)d_ws, out);
        ComputeTotalSim_finalize<<<(NPIX + 255) / 256, 256, 0, stream>>>(
            (const float*)d_ws, out);
    } else {
        // Fallback: one block does all channels, writes output directly.
        dim3 grid(1, HH / 4, BB);
        ComputeTotalSim_84267258347855_kernel<CC, true>
            <<<grid, 256, 0, stream>>>(feat, nullptr, out);
    }
}

// Round 6
// 49.146 us; speedup vs baseline: 3.6275x; 1.1091x over previous
//
#include <hip/hip_runtime.h>
#include <hip/hip_bf16.h>

// Problem constants: features [16, 512, 56, 56] f32, k=3 -> d=1
#define BB 16
#define CC 512
#define HH 56
#define WW 56
#define HW (HH * WW)
#define NPIX (BB * HW)   // 50176 output pixels
#define CGROUPS 8

__device__ __forceinline__ float shfl64(float v, int srcLane) {
    return __shfl(v, srcLane, 64);
}
__device__ __forceinline__ float xor32(float v) {
    return __shfl_xor(v, 32, 64);
}

// Proven math (rounds 1/2/5, absmax 2e-3 < 9e-3); masks & 1/9 cancel in cosine:
//   V  = mym*g(y-1) + g(y) + myp*g(y+1)
//   w3 = mym*g(y)   + g(cl(y+1)) + myp*g(cl(y+2))
//   w4 = mym*g(cl(y-2)) + g(cl(y-1)) + myp*g(y)
//   f1(x) = mxm*V(cl(x-2)) + V(cl(x-1)) + mxp*V(x)
//   f2(x) = mxm*V(x) + V(cl(x+1)) + mxp*V(cl(x+2))
//   f3(x) = mxm*w3(cl(x-1)) + w3(x) + mxp*w3(cl(x+1))
//   f4(x) = mxm*w4(cl(x-1)) + w4(x) + mxp*w4(cl(x+1))
// Wave = one row y. lane = sc*32 + h: sc = channel sub-group (2 channels per
// iter per wave), h = x-pair (float2, h<28 active). Halos via 8 bpermutes per
// iter (per 2 channels — half of round 5's rate); 2-stage load pipeline.
// Epilogue: cross-sc shfl_xor reduce, then PLAIN coalesced stores into a
// per-cgroup slab (no atomics, no memset needed); finalize sums 8 slabs.
template <int NITER, bool WRITE_OUT>
__global__ __launch_bounds__(256) void ComputeTotalSim_84267258347855_kernel(
    const float* __restrict__ feat, float* __restrict__ ws, float* __restrict__ out) {
    const int wave = threadIdx.x >> 6;
    const int lane = threadIdx.x & 63;
    const int sc = lane >> 5;
    const int h = lane & 31;
    const int b = blockIdx.z;
    const int cg = blockIdx.x;
    const int y = blockIdx.y * 4 + wave;

    const int x0 = (h <= 27) ? 2 * h : 54;  // idle lanes load safe real data

    const float mym  = (y >= 1) ? 1.f : 0.f;
    const float myp  = (y <= HH - 2) ? 1.f : 0.f;
    const float mxm0 = (h == 0) ? 0.f : 1.f;   // x=2h   >= 1 fails only at h=0
    const float mxp1 = (h >= 27) ? 0.f : 1.f;  // x=2h+1 <= 54 fails only at h=27

    const int ry0 = (y - 2 < 0) ? 0 : y - 2;
    const int ry1 = (y - 1 < 0) ? 0 : y - 1;
    const int ry3 = (y + 1 > HH - 1) ? HH - 1 : y + 1;
    const int ry4 = (y + 2 > HH - 1) ? HH - 1 : y + 2;
    const int o0 = ry0 * WW + x0, o1 = ry1 * WW + x0, o2 = y * WW + x0,
              o3 = ry3 * WW + x0, o4 = ry4 * WW + x0;

    // channels: cg*(2*NITER) + sc + 2*k, k = 0..NITER-1
    const float* p = feat + ((size_t)b * CC + (size_t)cg * (2 * NITER) + sc) * HW;

    float sAx = 0.f, sAy = 0.f, sBx = 0.f, sBy = 0.f, sCx = 0.f, sCy = 0.f;
    float sDx = 0.f, sDy = 0.f, sEx = 0.f, sEy = 0.f, sFx = 0.f, sFy = 0.f;

#define STEP(A0, A1, A2, A3, A4)                                                \
    {                                                                           \
        const float Vx  = fmaf(mym, A1.x, fmaf(myp, A3.x, A2.x));               \
        const float Vy  = fmaf(mym, A1.y, fmaf(myp, A3.y, A2.y));               \
        const float w3x = fmaf(mym, A2.x, fmaf(myp, A4.x, A3.x));               \
        const float w3y = fmaf(mym, A2.y, fmaf(myp, A4.y, A3.y));               \
        const float w4x = fmaf(mym, A0.x, fmaf(myp, A2.x, A1.x));               \
        const float w4y = fmaf(mym, A0.y, fmaf(myp, A2.y, A1.y));               \
        const float Lmx = shfl64(Vx, lane - 1);                                 \
        float       Lmy = shfl64(Vy, lane - 1);                                 \
        float       Rpx = shfl64(Vx, lane + 1);                                 \
        const float Rpy = shfl64(Vy, lane + 1);                                 \
        const float Lw3 = shfl64(w3y, lane - 1);                                \
        const float Rw3 = shfl64(w3x, lane + 1);                                \
        const float Lw4 = shfl64(w4y, lane - 1);                                \
        const float Rw4 = shfl64(w4x, lane + 1);                                \
        if (h == 0)  Lmy = Vx;   /* other left-halo uses are masked by mxm0 */  \
        if (h >= 27) Rpx = Vy;   /* other right-halo uses are masked by mxp1 */ \
        const float tL = Lmy + Vx;                                              \
        const float tR = Vy + Rpx;                                              \
        const float t3 = w3x + w3y;                                             \
        const float t4 = w4x + w4y;                                             \
        const float f1_0 = fmaf(mxm0, Lmx, tL);                                 \
        const float f1_1 = fmaf(mxp1, Vy, tL);                                  \
        const float f2_0 = fmaf(mxm0, Vx, tR);                                  \
        const float f2_1 = fmaf(mxp1, Rpy, tR);                                 \
        const float f3_0 = fmaf(mxm0, Lw3, t3);                                 \
        const float f3_1 = fmaf(mxp1, Rw3, t3);                                 \
        const float f4_0 = fmaf(mxm0, Lw4, t4);                                 \
        const float f4_1 = fmaf(mxp1, Rw4, t4);                                 \
        sAx = fmaf(f1_0, f2_0, sAx); sAy = fmaf(f1_1, f2_1, sAy);               \
        sBx = fmaf(f1_0, f1_0, sBx); sBy = fmaf(f1_1, f1_1, sBy);               \
        sCx = fmaf(f2_0, f2_0, sCx); sCy = fmaf(f2_1, f2_1, sCy);               \
        sDx = fmaf(f3_0, f4_0, sDx); sDy = fmaf(f3_1, f4_1, sDy);               \
        sEx = fmaf(f3_0, f3_0, sEx); sEy = fmaf(f3_1, f3_1, sEy);               \
        sFx = fmaf(f4_0, f4_0, sFx); sFy = fmaf(f4_1, f4_1, sFy);               \
    }

    // ---- 2-stage software pipeline over channel pairs (stride 2 channels) ----
    float2 A0 = *(const float2*)(p + o0), A1 = *(const float2*)(p + o1),
           A2 = *(const float2*)(p + o2), A3 = *(const float2*)(p + o3),
           A4 = *(const float2*)(p + o4);
    p += 2 * HW;
#pragma unroll 2
    for (int k = 0; k + 2 <= NITER; k += 2) {
        const float2 B0 = *(const float2*)(p + o0), B1 = *(const float2*)(p + o1),
                     B2 = *(const float2*)(p + o2), B3 = *(const float2*)(p + o3),
                     B4 = *(const float2*)(p + o4);
        STEP(A0, A1, A2, A3, A4);
        const float* pn = (k + 2 < NITER) ? p + 2 * HW : p;  // last pair: dummy re-read
        A0 = *(const float2*)(pn + o0); A1 = *(const float2*)(pn + o1);
        A2 = *(const float2*)(pn + o2); A3 = *(const float2*)(pn + o3);
        A4 = *(const float2*)(pn + o4);
        STEP(B0, B1, B2, B3, B4);
        p = pn + 2 * HW;
    }
#undef STEP

    // ---- cross-sc reduction (sum the two channel sub-groups) ----
    sAx += xor32(sAx); sAy += xor32(sAy);
    sBx += xor32(sBx); sBy += xor32(sBy);
    sCx += xor32(sCx); sCy += xor32(sCy);
    sDx += xor32(sDx); sDy += xor32(sDy);
    sEx += xor32(sEx); sEy += xor32(sEy);
    sFx += xor32(sFx); sFy += xor32(sFy);

    if (lane < 28) {  // sc==0, h<28
        const int pix = b * HW + y * WW + 2 * h;
        if (WRITE_OUT) {
            const double n0 = 0.5 * ((double)sAx / sqrt((double)sBx * (double)sCx) +
                                     (double)sDx / sqrt((double)sEx * (double)sFx));
            const double n1 = 0.5 * ((double)sAy / sqrt((double)sBy * (double)sCy) +
                                     (double)sDy / sqrt((double)sEy * (double)sFy));
            *(float2*)(out + pix) = make_float2((float)n0, (float)n1);
        } else {
            float* slab = ws + (size_t)cg * 6 * NPIX;
            *(float2*)(slab + 0 * NPIX + pix) = make_float2(sAx, sAy);
            *(float2*)(slab + 1 * NPIX + pix) = make_float2(sBx, sBy);
            *(float2*)(slab + 2 * NPIX + pix) = make_float2(sCx, sCy);
            *(float2*)(slab + 3 * NPIX + pix) = make_float2(sDx, sDy);
            *(float2*)(slab + 4 * NPIX + pix) = make_float2(sEx, sEy);
            *(float2*)(slab + 5 * NPIX + pix) = make_float2(sFx, sFy);
        }
    }
}

__global__ void ComputeTotalSim_finalize(const float* __restrict__ ws,
                                         float* __restrict__ out) {
    const int i = blockIdx.x * blockDim.x + threadIdx.x;
    if (i < NPIX) {
        double a0 = 0, a1 = 0, a2 = 0, a3 = 0, a4 = 0, a5 = 0;
#pragma unroll
        for (int cg = 0; cg < CGROUPS; ++cg) {
            const float* slab = ws + (size_t)cg * 6 * NPIX;
            a0 += slab[0 * NPIX + i];
            a1 += slab[1 * NPIX + i];
            a2 += slab[2 * NPIX + i];
            a3 += slab[3 * NPIX + i];
            a4 += slab[4 * NPIX + i];
            a5 += slab[5 * NPIX + i];
        }
        out[i] = (float)(0.5 * (a0 / sqrt(a1 * a2) + a3 / sqrt(a4 * a5)));
    }
}

extern "C" void kernel_launch(void* const* d_in, const int* in_sizes, int n_in,
                              void* d_out, int out_size, void* d_ws, size_t ws_size,
                              hipStream_t stream) {
    const float* feat = (const float*)d_in[0];
    float* out = (float*)d_out;

    const size_t need = (size_t)CGROUPS * 6 * NPIX * sizeof(float);  // 9.6 MB
    if (ws_size >= need) {
        // Phase 1: per-cgroup slab partials (plain stores, every slot written
        // every call -> no memset needed). Phase 2: sum slabs + cosine.
        dim3 grid(CGROUPS, HH / 4, BB);  // 8 x 14 x 16 = 1792 blocks
        ComputeTotalSim_84267258347855_kernel<CC / (2 * CGROUPS), false>
            <<<grid, 256, 0, stream>>>(feat, (float*)d_ws, out);
        ComputeTotalSim_finalize<<<(NPIX + 255) / 256, 256, 0, stream>>>(
            (const float*)d_ws, out);
    } else {
        // Fallback: single cgroup covers all 512 channels, writes out directly.
        dim3 grid(1, HH / 4, BB);
        ComputeTotalSim_84267258347855_kernel<CC / 2, true>
            <<<grid, 256, 0, stream>>>(feat, nullptr, out);
    }
}